// Round 9
// baseline (981.379 us; speedup 1.0000x reference)
//
#include <hip/hip_runtime.h>
#include <math.h>

#define DIM 64
#define NT 4
#define NR 8
// tmeta layout: [0..3]=tcnt  [4..7]=tbase  [8..11]=tfill  [12]=padded_total

// ---- bf16 helpers (bit-level; values finite/small) ----
__device__ __forceinline__ unsigned short f2bf(float f) {
    unsigned u = __float_as_uint(f);
    return (unsigned short)((u + 0x7FFF + ((u >> 16) & 1)) >> 16);  // RNE
}
__device__ __forceinline__ float bf2f(unsigned short u) {
    return __uint_as_float((unsigned)u << 16);
}
__device__ __forceinline__ float4 bf4_to_f4(ushort4 u) {
    float4 f;
    f.x = bf2f(u.x); f.y = bf2f(u.y); f.z = bf2f(u.z); f.w = bf2f(u.w);
    return f;
}

__global__ void init_cnt8(int* __restrict__ cnt, int* __restrict__ cnt2, int M) {
    int i = blockIdx.x * blockDim.x + threadIdx.x;
    if (i < M) { cnt[i] = 0; cnt2[i] = 0; }
}

__global__ void init_order(int* __restrict__ order, int* __restrict__ tm, int cap) {
    int i = blockIdx.x * blockDim.x + threadIdx.x;
    if (i < cap) order[i] = -1;
    if (i < 16) tm[i] = 0;
}

// ---- per-wave ballot histogram of node types ----
__global__ void type_count(const int* __restrict__ ntype, int* __restrict__ tm, int N) {
    int i = blockIdx.x * blockDim.x + threadIdx.x;
    int t = (i < N) ? ntype[i] : -1;
    int lane = threadIdx.x & 63;
    #pragma unroll
    for (int tt = 0; tt < NT; tt++) {
        unsigned long long m = __ballot(t == tt);
        int c = __popcll(m);
        if (c && lane == (__ffsll((long long)m) - 1)) atomicAdd(&tm[tt], c);
    }
}

__global__ void type_scan(int* __restrict__ tm) {
    if (threadIdx.x == 0 && blockIdx.x == 0) {
        int b = 0;
        for (int t = 0; t < NT; t++) { tm[4 + t] = b; b += ((tm[t] + 63) >> 6) << 6; }
        tm[12] = b;
    }
}

__global__ void type_scatter(const int* __restrict__ ntype, int* __restrict__ tm,
                             int* __restrict__ order, int N) {
    int i = blockIdx.x * blockDim.x + threadIdx.x;
    int t = (i < N) ? ntype[i] : -1;
    int lane = threadIdx.x & 63;
    #pragma unroll
    for (int tt = 0; tt < NT; tt++) {
        unsigned long long m = __ballot(t == tt);
        int c = __popcll(m);
        if (!c) continue;
        int ldr = __ffsll((long long)m) - 1;
        int base = 0;
        if (lane == ldr) base = atomicAdd(&tm[8 + tt], c);
        base = __shfl(base, ldr, 64);
        if (t == tt) {
            int rank = __popcll(m & ((1ull << lane) - 1ull));
            order[tm[4 + tt] + base + rank] = i;
        }
    }
}

// ---- typed K/Q/V projection: 64-node tile; k,v out bf16, q out fp32 ----
__global__ void proj_typed(const float* __restrict__ h, const int* __restrict__ ntype,
                           const int* __restrict__ order, const int* __restrict__ tm,
                           const float* __restrict__ Wk, const float* __restrict__ Wq,
                           const float* __restrict__ Wv,
                           unsigned short* __restrict__ kbf, float* __restrict__ q,
                           unsigned short* __restrict__ vbf, int N) {
    __shared__ float xs[64][68];
    __shared__ float wsm[64][64];
    int t  = threadIdx.x;
    int n0 = blockIdx.x * 64;
    if (n0 >= tm[12]) return;
    int first = order[n0];
    if (first < 0) return;
    int ty = ntype[first];

    #pragma unroll
    for (int i = 0; i < 4; i++) {
        int idx = t + 256 * i;
        int row = idx >> 4, c4 = idx & 15;
        int gn = order[n0 + row];
        float4 xv = make_float4(0.f, 0.f, 0.f, 0.f);
        if (gn >= 0) xv = ((const float4*)(h + (size_t)gn * DIM))[c4];
        ((float4*)&xs[row][0])[c4] = xv;
    }

    const float* Ws[3] = { Wk + (size_t)ty * DIM * DIM,
                           Wq + (size_t)ty * DIM * DIM,
                           Wv + (size_t)ty * DIM * DIM };

    int og  = t & 15;
    int ng4 = (t >> 4) * 4;
    int g[4];
    #pragma unroll
    for (int j = 0; j < 4; j++) g[j] = order[n0 + ng4 + j];

    for (int mm = 0; mm < 3; mm++) {
        const float4* wg = (const float4*)Ws[mm];
        float4* wl = (float4*)&wsm[0][0];
        __syncthreads();
        #pragma unroll
        for (int i = 0; i < 4; i++) wl[t + 256 * i] = wg[t + 256 * i];
        __syncthreads();
        float4 a[4];
        #pragma unroll
        for (int j = 0; j < 4; j++) a[j] = make_float4(0.f, 0.f, 0.f, 0.f);
        #pragma unroll 8
        for (int d = 0; d < DIM; d++) {
            float4 wv = ((const float4*)&wsm[d][0])[og];
            #pragma unroll
            for (int j = 0; j < 4; j++) {
                float xx = xs[ng4 + j][d];
                a[j].x = fmaf(xx, wv.x, a[j].x); a[j].y = fmaf(xx, wv.y, a[j].y);
                a[j].z = fmaf(xx, wv.z, a[j].z); a[j].w = fmaf(xx, wv.w, a[j].w);
            }
        }
        if (mm == 1) {
            #pragma unroll
            for (int j = 0; j < 4; j++)
                if (g[j] >= 0) ((float4*)(q + (size_t)g[j] * DIM))[og] = a[j];
        } else {
            unsigned short* ob = (mm == 0) ? kbf : vbf;
            #pragma unroll
            for (int j = 0; j < 4; j++)
                if (g[j] >= 0)
                    ((ushort4*)(ob + (size_t)g[j] * DIM))[og] =
                        make_ushort4(f2bf(a[j].x), f2bf(a[j].y), f2bf(a[j].z), f2bf(a[j].w));
        }
    }
}

// ---------------- CSR build over (dst*8 + etype) buckets ----------------
__global__ void hist8(const int* __restrict__ dst, const int* __restrict__ et,
                      int* __restrict__ cnt, int E) {
    int e = blockIdx.x * blockDim.x + threadIdx.x;
    if (e < E) atomicAdd(&cnt[dst[e] * NR + et[e]], 1);
}

__global__ void scan1(const int* __restrict__ cnt, int* __restrict__ off,
                      int* __restrict__ bsum, int M) {
    __shared__ int buf[1024];
    int tid = threadIdx.x;
    int i = blockIdx.x * 1024 + tid;
    int x = (i < M) ? cnt[i] : 0;
    buf[tid] = x;
    __syncthreads();
    for (int s = 1; s < 1024; s <<= 1) {
        int t = (tid >= s) ? buf[tid - s] : 0;
        __syncthreads();
        buf[tid] += t;
        __syncthreads();
    }
    if (i < M) off[i] = buf[tid] - x;
    if (tid == 1023) bsum[blockIdx.x] = buf[1023];
}

__global__ void scan2(int* __restrict__ bsum, int nb) {
    __shared__ int buf[1024];
    __shared__ int carry;
    int tid = threadIdx.x;
    if (tid == 0) carry = 0;
    __syncthreads();
    for (int base = 0; base < nb; base += 1024) {
        int i = base + tid;
        int x = (i < nb) ? bsum[i] : 0;
        buf[tid] = x;
        __syncthreads();
        for (int s = 1; s < 1024; s <<= 1) {
            int t = (tid >= s) ? buf[tid - s] : 0;
            __syncthreads();
            buf[tid] += t;
            __syncthreads();
        }
        if (i < nb) bsum[i] = carry + buf[tid] - x;
        __syncthreads();
        if (tid == 1023) carry += buf[1023];
        __syncthreads();
    }
}

__global__ void scan3(int* __restrict__ off, const int* __restrict__ bsum, int M, int E) {
    int i = blockIdx.x * 1024 + threadIdx.x;
    if (i < M) off[i] += bsum[blockIdx.x];
    if (i == 0) off[M] = E;
}

__global__ void scatter8(const int* __restrict__ src, const int* __restrict__ dst,
                         const int* __restrict__ et, const int* __restrict__ off,
                         int* __restrict__ cnt2, int* __restrict__ se, int E) {
    int e = blockIdx.x * blockDim.x + threadIdx.x;
    if (e >= E) return;
    int key = dst[e] * NR + et[e];
    int p = off[key] + atomicAdd(&cnt2[key], 1);
    se[p] = src[e];
}

// ---- fused score: 16 nodes/block; ts[r] = q_tile @ A_r in LDS (bf16),
// then single relation-bucketed edge walk gathering bf16 k (L2-resident) ----
__global__ void score_fused2(const float* __restrict__ q, const unsigned short* __restrict__ kbf,
                             const int* __restrict__ se, const int* __restrict__ off8,
                             const float* __restrict__ A, const float* __restrict__ rel_pri,
                             float* __restrict__ ex, float* __restrict__ den, int N) {
    __shared__ float qs[16][68];
    __shared__ float As[64][64];
    __shared__ unsigned short ts[NR][16][64];
    __shared__ float prs[NR];
    int t = threadIdx.x;
    int n0 = blockIdx.x * 16;
    int node = t >> 4;
    int og   = t & 15;
    int ll   = og;

    if (t < NR) prs[t] = rel_pri[t] * 0.125f;
    {
        int row = node, c4 = og;
        int gn = n0 + row;
        float4 xv = make_float4(0.f, 0.f, 0.f, 0.f);
        if (gn < N) xv = ((const float4*)(q + (size_t)gn * DIM))[c4];
        ((float4*)&qs[row][0])[c4] = xv;
    }

    for (int r = 0; r < NR; r++) {
        __syncthreads();
        const float4* ag = (const float4*)(A + (size_t)r * DIM * DIM);
        float4* al = (float4*)&As[0][0];
        #pragma unroll
        for (int i = 0; i < 4; i++) al[t + 256 * i] = ag[t + 256 * i];
        __syncthreads();
        float4 acc = make_float4(0.f, 0.f, 0.f, 0.f);
        #pragma unroll 8
        for (int d = 0; d < DIM; d++) {
            float xv = qs[node][d];
            float4 wv = ((const float4*)&As[d][0])[og];
            acc.x = fmaf(xv, wv.x, acc.x); acc.y = fmaf(xv, wv.y, acc.y);
            acc.z = fmaf(xv, wv.z, acc.z); acc.w = fmaf(xv, wv.w, acc.w);
        }
        ((ushort4*)&ts[r][node][0])[og] =
            make_ushort4(f2bf(acc.x), f2bf(acc.y), f2bf(acc.z), f2bf(acc.w));
    }
    __syncthreads();

    int n = n0 + node;
    if (n >= N) return;
    float dl = 0.f;
    for (int r = 0; r < NR; r++) {
        int i0 = off8[n * NR + r], i1 = off8[n * NR + r + 1];
        if (i0 == i1) continue;
        float4 tv = bf4_to_f4(((const ushort4*)&ts[r][node][0])[ll]);
        float pri = prs[r];
        for (int i = i0; i < i1; i++) {
            int s = se[i];
            float4 kv = bf4_to_f4(((const ushort4*)(kbf + (size_t)s * DIM))[ll]);
            float p = tv.x * kv.x + tv.y * kv.y + tv.z * kv.z + tv.w * kv.w;
            p += __shfl_xor(p, 8, 16);
            p += __shfl_xor(p, 4, 16);
            p += __shfl_xor(p, 2, 16);
            p += __shfl_xor(p, 1, 16);
            if (ll == 0) {
                float e_ = expf(p * pri);   // logits tiny by input scaling: no max-shift
                ex[i] = e_;
                dl += e_;
            }
        }
    }
    if (ll == 0) den[n] = dl;
}

// ---- fused aggregate: y_r = sum alpha*v[s] (fp32 regs, contiguous per relation),
// flush to bf16 LDS, then agg = sum_r y_r @ W_r with W_r staged per pass ----
__global__ void agg_fused2(const unsigned short* __restrict__ vbf, const float* __restrict__ ex,
                           const int* __restrict__ se, const int* __restrict__ off8,
                           const float* __restrict__ Mw, const float* __restrict__ den,
                           float* __restrict__ agg, int N) {
    __shared__ unsigned short ys[NR][16][64];
    __shared__ float Wsm[64][64];
    int t = threadIdx.x;
    int n0 = blockIdx.x * 16;
    int node = t >> 4;
    int og   = t & 15;
    int ll   = og;
    int n = n0 + node;

    if (n < N) {
        float dn = den[n];
        float inv = (dn == 0.f) ? 0.f : 1.f / dn;
        for (int r = 0; r < NR; r++) {
            int i0 = off8[n * NR + r], i1 = off8[n * NR + r + 1];
            float4 y = make_float4(0.f, 0.f, 0.f, 0.f);
            for (int i = i0; i < i1; i++) {
                int s = se[i];
                float alpha = ex[i] * inv;
                float4 vv = bf4_to_f4(((const ushort4*)(vbf + (size_t)s * DIM))[ll]);
                y.x = fmaf(alpha, vv.x, y.x);
                y.y = fmaf(alpha, vv.y, y.y);
                y.z = fmaf(alpha, vv.z, y.z);
                y.w = fmaf(alpha, vv.w, y.w);
            }
            ((ushort4*)&ys[r][node][0])[ll] =
                make_ushort4(f2bf(y.x), f2bf(y.y), f2bf(y.z), f2bf(y.w));
        }
    } else {
        ushort4 z = make_ushort4(0, 0, 0, 0);
        #pragma unroll
        for (int r = 0; r < NR; r++) ((ushort4*)&ys[r][node][0])[ll] = z;
    }

    float4 c = make_float4(0.f, 0.f, 0.f, 0.f);
    for (int r = 0; r < NR; r++) {
        __syncthreads();
        const float4* wg = (const float4*)(Mw + (size_t)r * DIM * DIM);
        float4* wl = (float4*)&Wsm[0][0];
        #pragma unroll
        for (int i = 0; i < 4; i++) wl[t + 256 * i] = wg[t + 256 * i];
        __syncthreads();
        #pragma unroll 8
        for (int d = 0; d < DIM; d++) {
            float yv = bf2f(ys[r][node][d]);
            float4 wv = ((const float4*)&Wsm[d][0])[og];
            c.x = fmaf(yv, wv.x, c.x); c.y = fmaf(yv, wv.y, c.y);
            c.z = fmaf(yv, wv.z, c.z); c.w = fmaf(yv, wv.w, c.w);
        }
    }
    if (n < N) ((float4*)(agg + (size_t)n * DIM))[og] = c;
}

// ------- typed output GEMM: 64-node tile, sigmoid(skip)*W staged in LDS -------
__global__ void out_typed(const float* __restrict__ agg, const int* __restrict__ ntype,
                          const int* __restrict__ order, const int* __restrict__ tm,
                          const float* __restrict__ Wa, const float* __restrict__ skip,
                          float* __restrict__ out, int N) {
    __shared__ float xs[64][68];
    __shared__ float wsm[64][64];
    int t  = threadIdx.x;
    int n0 = blockIdx.x * 64;
    if (n0 >= tm[12]) return;
    int first = order[n0];
    if (first < 0) return;
    int ty = ntype[first];
    float sg = 1.f / (1.f + expf(-skip[ty]));

    const float4* wg = (const float4*)(Wa + (size_t)ty * DIM * DIM);
    float4* wl = (float4*)&wsm[0][0];
    #pragma unroll
    for (int i = 0; i < 4; i++) {
        float4 w = wg[t + 256 * i];
        w.x *= sg; w.y *= sg; w.z *= sg; w.w *= sg;
        wl[t + 256 * i] = w;
    }
    #pragma unroll
    for (int i = 0; i < 4; i++) {
        int idx = t + 256 * i;
        int row = idx >> 4, c4 = idx & 15;
        int gn = order[n0 + row];
        float4 xv = make_float4(0.f, 0.f, 0.f, 0.f);
        if (gn >= 0) xv = ((const float4*)(agg + (size_t)gn * DIM))[c4];
        ((float4*)&xs[row][0])[c4] = xv;
    }
    __syncthreads();

    int og  = t & 15;
    int ng4 = (t >> 4) * 4;
    float4 a0 = make_float4(0.f,0.f,0.f,0.f), a1 = a0, a2 = a0, a3 = a0;
    #pragma unroll 8
    for (int d = 0; d < DIM; d++) {
        float4 wv = ((const float4*)&wsm[d][0])[og];
        float x0 = xs[ng4 + 0][d];
        float x1 = xs[ng4 + 1][d];
        float x2 = xs[ng4 + 2][d];
        float x3 = xs[ng4 + 3][d];
        a0.x = fmaf(x0, wv.x, a0.x); a0.y = fmaf(x0, wv.y, a0.y);
        a0.z = fmaf(x0, wv.z, a0.z); a0.w = fmaf(x0, wv.w, a0.w);
        a1.x = fmaf(x1, wv.x, a1.x); a1.y = fmaf(x1, wv.y, a1.y);
        a1.z = fmaf(x1, wv.z, a1.z); a1.w = fmaf(x1, wv.w, a1.w);
        a2.x = fmaf(x2, wv.x, a2.x); a2.y = fmaf(x2, wv.y, a2.y);
        a2.z = fmaf(x2, wv.z, a2.z); a2.w = fmaf(x2, wv.w, a2.w);
        a3.x = fmaf(x3, wv.x, a3.x); a3.y = fmaf(x3, wv.y, a3.y);
        a3.z = fmaf(x3, wv.z, a3.z); a3.w = fmaf(x3, wv.w, a3.w);
    }
    int g0 = order[n0 + ng4 + 0];
    int g1 = order[n0 + ng4 + 1];
    int g2 = order[n0 + ng4 + 2];
    int g3 = order[n0 + ng4 + 3];
    if (g0 >= 0) ((float4*)(out + (size_t)g0 * DIM))[og] = a0;
    if (g1 >= 0) ((float4*)(out + (size_t)g1 * DIM))[og] = a1;
    if (g2 >= 0) ((float4*)(out + (size_t)g2 * DIM))[og] = a2;
    if (g3 >= 0) ((float4*)(out + (size_t)g3 * DIM))[og] = a3;
}

extern "C" void kernel_launch(void* const* d_in, const int* in_sizes, int n_in,
                              void* d_out, int out_size, void* d_ws, size_t ws_size,
                              hipStream_t stream) {
    const float* h       = (const float*)d_in[0];
    const int*   ntype   = (const int*)  d_in[1];
    const int*   src     = (const int*)  d_in[2];
    const int*   dst     = (const int*)  d_in[3];
    const int*   et      = (const int*)  d_in[4];
    const float* k_lin   = (const float*)d_in[5];
    const float* q_lin   = (const float*)d_in[6];
    const float* v_lin   = (const float*)d_in[7];
    const float* a_lin   = (const float*)d_in[8];
    const float* rel_att = (const float*)d_in[9];
    const float* rel_msg = (const float*)d_in[10];
    const float* rel_pri = (const float*)d_in[11];
    const float* skip    = (const float*)d_in[12];

    int N = in_sizes[1];
    int E = in_sizes[2];
    int M = N * NR;               // bucket count
    int ocap = N + NT * 64;

    float* ws = (float*)d_ws;
    size_t o = 0;
    unsigned short* kbf = (unsigned short*)(ws + o); o += (size_t)N * DIM / 2;
    float* q    = ws + o; o += (size_t)N * DIM;      // agg overlays q (dead after score)
    unsigned short* vbf = (unsigned short*)(ws + o); o += (size_t)N * DIM / 2;
    float* ex   = ws + o; o += (size_t)E;
    float* den  = ws + o; o += (size_t)N;
    int* off8   = (int*)(ws + o); o += (size_t)M + 8;
    int* cnt8   = (int*)(ws + o); o += (size_t)M;
    int* cnt28  = (int*)(ws + o); o += (size_t)M;
    int* se     = (int*)(ws + o); o += (size_t)E;
    int* bsum   = (int*)(ws + o); o += 1024;
    int* order  = (int*)(ws + o); o += (size_t)ocap;
    int* tm     = (int*)(ws + o); o += 16;
    float* agg  = q;   // q dead after score_fused2; agg written in agg_fused2

    float* out = (float*)d_out;

    // ---- type sort ----
    init_order<<<(ocap + 255) / 256, 256, 0, stream>>>(order, tm, ocap);
    type_count<<<(N + 255) / 256, 256, 0, stream>>>(ntype, tm, N);
    type_scan<<<1, 64, 0, stream>>>(tm);
    type_scatter<<<(N + 255) / 256, 256, 0, stream>>>(ntype, tm, order, N);

    // ---- typed fused projections (k,v -> bf16, q -> fp32) ----
    int gridT = (N + NT * 64 + 63) / 64;
    proj_typed<<<gridT, 256, 0, stream>>>(h, ntype, order, tm, k_lin, q_lin, v_lin,
                                          kbf, q, vbf, N);

    // ---- CSR build over (dst, etype) buckets ----
    init_cnt8<<<(M + 255) / 256, 256, 0, stream>>>(cnt8, cnt28, M);
    hist8<<<(E + 255) / 256, 256, 0, stream>>>(dst, et, cnt8, E);
    int nb = (M + 1023) / 1024;
    scan1<<<nb, 1024, 0, stream>>>(cnt8, off8, bsum, M);
    scan2<<<1, 1024, 0, stream>>>(bsum, nb);
    scan3<<<nb, 1024, 0, stream>>>(off8, bsum, M, E);
    scatter8<<<(E + 255) / 256, 256, 0, stream>>>(src, dst, et, off8, cnt28, se, E);

    // ---- fused score + aggregate (no qW/vW materialization) ----
    int nb16 = (N + 15) / 16;
    score_fused2<<<nb16, 256, 0, stream>>>(q, kbf, se, off8, rel_att, rel_pri, ex, den, N);
    agg_fused2<<<nb16, 256, 0, stream>>>(vbf, ex, se, off8, rel_msg, den, agg, N);

    // ---- typed output GEMM ----
    out_typed<<<gridT, 256, 0, stream>>>(agg, ntype, order, tm, a_lin, skip, out, N);
}

// Round 10
// 893.761 us; speedup vs baseline: 1.0980x; 1.0980x over previous
//
#include <hip/hip_runtime.h>
#include <math.h>

#define DIM 64
#define NT 4
#define NR 8
// tmeta layout: [0..3]=tcnt  [4..7]=tbase  [8..11]=tfill  [12]=padded_total

// ---- bf16 helpers (bit-level; values finite/small) ----
__device__ __forceinline__ unsigned short f2bf(float f) {
    unsigned u = __float_as_uint(f);
    return (unsigned short)((u + 0x7FFF + ((u >> 16) & 1)) >> 16);  // RNE
}
__device__ __forceinline__ float bf2f(unsigned short u) {
    return __uint_as_float((unsigned)u << 16);
}
__device__ __forceinline__ float4 bf4_to_f4(ushort4 u) {
    float4 f;
    f.x = bf2f(u.x); f.y = bf2f(u.y); f.z = bf2f(u.z); f.w = bf2f(u.w);
    return f;
}

__global__ void init_cnt8(int* __restrict__ cnt, int* __restrict__ cnt2, int M) {
    int i = blockIdx.x * blockDim.x + threadIdx.x;
    if (i < M) { cnt[i] = 0; cnt2[i] = 0; }
}

__global__ void init_order(int* __restrict__ order, int* __restrict__ tm, int cap) {
    int i = blockIdx.x * blockDim.x + threadIdx.x;
    if (i < cap) order[i] = -1;
    if (i < 16) tm[i] = 0;
}

// ---- per-wave ballot histogram of node types ----
__global__ void type_count(const int* __restrict__ ntype, int* __restrict__ tm, int N) {
    int i = blockIdx.x * blockDim.x + threadIdx.x;
    int t = (i < N) ? ntype[i] : -1;
    int lane = threadIdx.x & 63;
    #pragma unroll
    for (int tt = 0; tt < NT; tt++) {
        unsigned long long m = __ballot(t == tt);
        int c = __popcll(m);
        if (c && lane == (__ffsll((long long)m) - 1)) atomicAdd(&tm[tt], c);
    }
}

__global__ void type_scan(int* __restrict__ tm) {
    if (threadIdx.x == 0 && blockIdx.x == 0) {
        int b = 0;
        for (int t = 0; t < NT; t++) { tm[4 + t] = b; b += ((tm[t] + 63) >> 6) << 6; }
        tm[12] = b;
    }
}

__global__ void type_scatter(const int* __restrict__ ntype, int* __restrict__ tm,
                             int* __restrict__ order, int N) {
    int i = blockIdx.x * blockDim.x + threadIdx.x;
    int t = (i < N) ? ntype[i] : -1;
    int lane = threadIdx.x & 63;
    #pragma unroll
    for (int tt = 0; tt < NT; tt++) {
        unsigned long long m = __ballot(t == tt);
        int c = __popcll(m);
        if (!c) continue;
        int ldr = __ffsll((long long)m) - 1;
        int base = 0;
        if (lane == ldr) base = atomicAdd(&tm[8 + tt], c);
        base = __shfl(base, ldr, 64);
        if (t == tt) {
            int rank = __popcll(m & ((1ull << lane) - 1ull));
            order[tm[4 + tt] + base + rank] = i;
        }
    }
}

// ---- typed K/Q/V projection: 64-node tile; k out bf16, q/v out fp32 ----
__global__ void proj_typed(const float* __restrict__ h, const int* __restrict__ ntype,
                           const int* __restrict__ order, const int* __restrict__ tm,
                           const float* __restrict__ Wk, const float* __restrict__ Wq,
                           const float* __restrict__ Wv,
                           unsigned short* __restrict__ kbf, float* __restrict__ q,
                           float* __restrict__ v, int N) {
    __shared__ float xs[64][68];
    __shared__ float wsm[64][64];
    int t  = threadIdx.x;
    int n0 = blockIdx.x * 64;
    if (n0 >= tm[12]) return;
    int first = order[n0];
    if (first < 0) return;
    int ty = ntype[first];

    #pragma unroll
    for (int i = 0; i < 4; i++) {
        int idx = t + 256 * i;
        int row = idx >> 4, c4 = idx & 15;
        int gn = order[n0 + row];
        float4 xv = make_float4(0.f, 0.f, 0.f, 0.f);
        if (gn >= 0) xv = ((const float4*)(h + (size_t)gn * DIM))[c4];
        ((float4*)&xs[row][0])[c4] = xv;
    }

    const float* Ws[3] = { Wk + (size_t)ty * DIM * DIM,
                           Wq + (size_t)ty * DIM * DIM,
                           Wv + (size_t)ty * DIM * DIM };

    int og  = t & 15;
    int ng4 = (t >> 4) * 4;
    int g[4];
    #pragma unroll
    for (int j = 0; j < 4; j++) g[j] = order[n0 + ng4 + j];

    for (int mm = 0; mm < 3; mm++) {
        const float4* wg = (const float4*)Ws[mm];
        float4* wl = (float4*)&wsm[0][0];
        __syncthreads();
        #pragma unroll
        for (int i = 0; i < 4; i++) wl[t + 256 * i] = wg[t + 256 * i];
        __syncthreads();
        float4 a[4];
        #pragma unroll
        for (int j = 0; j < 4; j++) a[j] = make_float4(0.f, 0.f, 0.f, 0.f);
        #pragma unroll 8
        for (int d = 0; d < DIM; d++) {
            float4 wv = ((const float4*)&wsm[d][0])[og];
            #pragma unroll
            for (int j = 0; j < 4; j++) {
                float xx = xs[ng4 + j][d];
                a[j].x = fmaf(xx, wv.x, a[j].x); a[j].y = fmaf(xx, wv.y, a[j].y);
                a[j].z = fmaf(xx, wv.z, a[j].z); a[j].w = fmaf(xx, wv.w, a[j].w);
            }
        }
        if (mm == 0) {
            #pragma unroll
            for (int j = 0; j < 4; j++)
                if (g[j] >= 0)
                    ((ushort4*)(kbf + (size_t)g[j] * DIM))[og] =
                        make_ushort4(f2bf(a[j].x), f2bf(a[j].y), f2bf(a[j].z), f2bf(a[j].w));
        } else {
            float* ob = (mm == 1) ? q : v;
            #pragma unroll
            for (int j = 0; j < 4; j++)
                if (g[j] >= 0) ((float4*)(ob + (size_t)g[j] * DIM))[og] = a[j];
        }
    }
}

// ---------------- CSR build over (dst*8 + etype) buckets ----------------
__global__ void hist8(const int* __restrict__ dst, const int* __restrict__ et,
                      int* __restrict__ cnt, int E) {
    int e = blockIdx.x * blockDim.x + threadIdx.x;
    if (e < E) atomicAdd(&cnt[dst[e] * NR + et[e]], 1);
}

__global__ void scan1(const int* __restrict__ cnt, int* __restrict__ off,
                      int* __restrict__ bsum, int M) {
    __shared__ int buf[1024];
    int tid = threadIdx.x;
    int i = blockIdx.x * 1024 + tid;
    int x = (i < M) ? cnt[i] : 0;
    buf[tid] = x;
    __syncthreads();
    for (int s = 1; s < 1024; s <<= 1) {
        int t = (tid >= s) ? buf[tid - s] : 0;
        __syncthreads();
        buf[tid] += t;
        __syncthreads();
    }
    if (i < M) off[i] = buf[tid] - x;
    if (tid == 1023) bsum[blockIdx.x] = buf[1023];
}

__global__ void scan2(int* __restrict__ bsum, int nb) {
    __shared__ int buf[1024];
    __shared__ int carry;
    int tid = threadIdx.x;
    if (tid == 0) carry = 0;
    __syncthreads();
    for (int base = 0; base < nb; base += 1024) {
        int i = base + tid;
        int x = (i < nb) ? bsum[i] : 0;
        buf[tid] = x;
        __syncthreads();
        for (int s = 1; s < 1024; s <<= 1) {
            int t = (tid >= s) ? buf[tid - s] : 0;
            __syncthreads();
            buf[tid] += t;
            __syncthreads();
        }
        if (i < nb) bsum[i] = carry + buf[tid] - x;
        __syncthreads();
        if (tid == 1023) carry += buf[1023];
        __syncthreads();
    }
}

__global__ void scan3(int* __restrict__ off, const int* __restrict__ bsum, int M, int E) {
    int i = blockIdx.x * 1024 + threadIdx.x;
    if (i < M) off[i] += bsum[blockIdx.x];
    if (i == 0) off[M] = E;
}

__global__ void scatter8(const int* __restrict__ src, const int* __restrict__ dst,
                         const int* __restrict__ et, const int* __restrict__ off,
                         int* __restrict__ cnt2, int* __restrict__ se, int E) {
    int e = blockIdx.x * blockDim.x + threadIdx.x;
    if (e >= E) return;
    int key = dst[e] * NR + et[e];
    int p = off[key] + atomicAdd(&cnt2[key], 1);
    se[p] = src[e];
}

// ---- apply_rel for ALL 8 relations in one block: x staged once, loop r ----
// out[r][n][o] (bf16) = sum_d x[n][d] * Wr[r][d][o]
__global__ void apply_rel8(const float* __restrict__ x, const float* __restrict__ Wr,
                           unsigned short* __restrict__ out, int N) {
    __shared__ float xs[64][68];
    __shared__ float wsm[64][64];
    int t  = threadIdx.x;
    int n0 = blockIdx.x * 64;

    #pragma unroll
    for (int i = 0; i < 4; i++) {
        int idx = t + 256 * i;
        int row = idx >> 4, c4 = idx & 15;
        int gn = n0 + row;
        float4 xv = make_float4(0.f, 0.f, 0.f, 0.f);
        if (gn < N) xv = ((const float4*)(x + (size_t)gn * DIM))[c4];
        ((float4*)&xs[row][0])[c4] = xv;
    }

    int og  = t & 15;
    int ng4 = (t >> 4) * 4;

    for (int r = 0; r < NR; r++) {
        const float4* wg = (const float4*)(Wr + (size_t)r * DIM * DIM);
        float4* wl = (float4*)&wsm[0][0];
        __syncthreads();          // prev compute done reading wsm (and xs staged, 1st iter)
        #pragma unroll
        for (int i = 0; i < 4; i++) wl[t + 256 * i] = wg[t + 256 * i];
        __syncthreads();
        float4 a[4];
        #pragma unroll
        for (int j = 0; j < 4; j++) a[j] = make_float4(0.f, 0.f, 0.f, 0.f);
        #pragma unroll 8
        for (int d = 0; d < DIM; d++) {
            float4 wv = ((const float4*)&wsm[d][0])[og];
            #pragma unroll
            for (int j = 0; j < 4; j++) {
                float xx = xs[ng4 + j][d];
                a[j].x = fmaf(xx, wv.x, a[j].x); a[j].y = fmaf(xx, wv.y, a[j].y);
                a[j].z = fmaf(xx, wv.z, a[j].z); a[j].w = fmaf(xx, wv.w, a[j].w);
            }
        }
        unsigned short* ob = out + (size_t)r * N * DIM;
        #pragma unroll
        for (int j = 0; j < 4; j++) {
            int gn = n0 + ng4 + j;
            if (gn < N)
                ((ushort4*)(ob + (size_t)gn * DIM))[og] =
                    make_ushort4(f2bf(a[j].x), f2bf(a[j].y), f2bf(a[j].z), f2bf(a[j].w));
        }
    }
}

// ---- score over bucketed CSR: 16-lane group per node; qW row hoisted per bucket ----
__global__ void score_b(const unsigned short* __restrict__ qW,
                        const unsigned short* __restrict__ kbf,
                        const int* __restrict__ se, const int* __restrict__ off8,
                        const float* __restrict__ rel_pri,
                        float* __restrict__ ex, float* __restrict__ den, int N) {
    int t = threadIdx.x;
    int node = t >> 4;
    int ll   = t & 15;
    int n = blockIdx.x * 16 + node;
    if (n >= N) return;
    // lanes 0..8 load the 9 bucket offsets; broadcast via shfl
    int ov = (ll < 9) ? off8[n * NR + ll] : 0;
    float dl = 0.f;
    #pragma unroll
    for (int r = 0; r < NR; r++) {
        int i0 = __shfl(ov, r, 16);
        int i1 = __shfl(ov, r + 1, 16);
        if (i0 == i1) continue;
        float4 tv = bf4_to_f4(((const ushort4*)(qW + ((size_t)r * N + n) * DIM))[ll]);
        float pri = rel_pri[r] * 0.125f;
        for (int i = i0; i < i1; i++) {
            int s = se[i];
            float4 kv = bf4_to_f4(((const ushort4*)(kbf + (size_t)s * DIM))[ll]);
            float p = tv.x * kv.x + tv.y * kv.y + tv.z * kv.z + tv.w * kv.w;
            p += __shfl_xor(p, 8, 16);
            p += __shfl_xor(p, 4, 16);
            p += __shfl_xor(p, 2, 16);
            p += __shfl_xor(p, 1, 16);
            if (ll == 0) {
                float e_ = expf(p * pri);   // logits tiny by input scaling: no max-shift
                ex[i] = e_;
                dl += e_;
            }
        }
    }
    if (ll == 0) den[n] = dl;
}

// ---- aggregate over bucketed CSR: single float4 accumulator per lane ----
__global__ void agg_b(const unsigned short* __restrict__ vW, const float* __restrict__ ex,
                      const int* __restrict__ se, const int* __restrict__ off8,
                      const float* __restrict__ den, float* __restrict__ agg, int N) {
    int t = threadIdx.x;
    int node = t >> 4;
    int ll   = t & 15;
    int n = blockIdx.x * 16 + node;
    if (n >= N) return;
    int ov = (ll < 9) ? off8[n * NR + ll] : 0;
    float dn = den[n];
    float inv = (dn == 0.f) ? 0.f : 1.f / dn;
    float4 acc = make_float4(0.f, 0.f, 0.f, 0.f);
    #pragma unroll
    for (int r = 0; r < NR; r++) {
        int i0 = __shfl(ov, r, 16);
        int i1 = __shfl(ov, r + 1, 16);
        const unsigned short* vr = vW + (size_t)r * N * DIM;
        for (int i = i0; i < i1; i++) {
            int s = se[i];
            float alpha = ex[i] * inv;
            float4 mv = bf4_to_f4(((const ushort4*)(vr + (size_t)s * DIM))[ll]);
            acc.x = fmaf(alpha, mv.x, acc.x);
            acc.y = fmaf(alpha, mv.y, acc.y);
            acc.z = fmaf(alpha, mv.z, acc.z);
            acc.w = fmaf(alpha, mv.w, acc.w);
        }
    }
    ((float4*)(agg + (size_t)n * DIM))[ll] = acc;
}

// ------- typed output GEMM: 64-node tile, sigmoid(skip)*W staged in LDS -------
__global__ void out_typed(const float* __restrict__ agg, const int* __restrict__ ntype,
                          const int* __restrict__ order, const int* __restrict__ tm,
                          const float* __restrict__ Wa, const float* __restrict__ skip,
                          float* __restrict__ out, int N) {
    __shared__ float xs[64][68];
    __shared__ float wsm[64][64];
    int t  = threadIdx.x;
    int n0 = blockIdx.x * 64;
    if (n0 >= tm[12]) return;
    int first = order[n0];
    if (first < 0) return;
    int ty = ntype[first];
    float sg = 1.f / (1.f + expf(-skip[ty]));

    const float4* wg = (const float4*)(Wa + (size_t)ty * DIM * DIM);
    float4* wl = (float4*)&wsm[0][0];
    #pragma unroll
    for (int i = 0; i < 4; i++) {
        float4 w = wg[t + 256 * i];
        w.x *= sg; w.y *= sg; w.z *= sg; w.w *= sg;
        wl[t + 256 * i] = w;
    }
    #pragma unroll
    for (int i = 0; i < 4; i++) {
        int idx = t + 256 * i;
        int row = idx >> 4, c4 = idx & 15;
        int gn = order[n0 + row];
        float4 xv = make_float4(0.f, 0.f, 0.f, 0.f);
        if (gn >= 0) xv = ((const float4*)(agg + (size_t)gn * DIM))[c4];
        ((float4*)&xs[row][0])[c4] = xv;
    }
    __syncthreads();

    int og  = t & 15;
    int ng4 = (t >> 4) * 4;
    float4 a0 = make_float4(0.f,0.f,0.f,0.f), a1 = a0, a2 = a0, a3 = a0;
    #pragma unroll 8
    for (int d = 0; d < DIM; d++) {
        float4 wv = ((const float4*)&wsm[d][0])[og];
        float x0 = xs[ng4 + 0][d];
        float x1 = xs[ng4 + 1][d];
        float x2 = xs[ng4 + 2][d];
        float x3 = xs[ng4 + 3][d];
        a0.x = fmaf(x0, wv.x, a0.x); a0.y = fmaf(x0, wv.y, a0.y);
        a0.z = fmaf(x0, wv.z, a0.z); a0.w = fmaf(x0, wv.w, a0.w);
        a1.x = fmaf(x1, wv.x, a1.x); a1.y = fmaf(x1, wv.y, a1.y);
        a1.z = fmaf(x1, wv.z, a1.z); a1.w = fmaf(x1, wv.w, a1.w);
        a2.x = fmaf(x2, wv.x, a2.x); a2.y = fmaf(x2, wv.y, a2.y);
        a2.z = fmaf(x2, wv.z, a2.z); a2.w = fmaf(x2, wv.w, a2.w);
        a3.x = fmaf(x3, wv.x, a3.x); a3.y = fmaf(x3, wv.y, a3.y);
        a3.z = fmaf(x3, wv.z, a3.z); a3.w = fmaf(x3, wv.w, a3.w);
    }
    int g0 = order[n0 + ng4 + 0];
    int g1 = order[n0 + ng4 + 1];
    int g2 = order[n0 + ng4 + 2];
    int g3 = order[n0 + ng4 + 3];
    if (g0 >= 0) ((float4*)(out + (size_t)g0 * DIM))[og] = a0;
    if (g1 >= 0) ((float4*)(out + (size_t)g1 * DIM))[og] = a1;
    if (g2 >= 0) ((float4*)(out + (size_t)g2 * DIM))[og] = a2;
    if (g3 >= 0) ((float4*)(out + (size_t)g3 * DIM))[og] = a3;
}

extern "C" void kernel_launch(void* const* d_in, const int* in_sizes, int n_in,
                              void* d_out, int out_size, void* d_ws, size_t ws_size,
                              hipStream_t stream) {
    const float* h       = (const float*)d_in[0];
    const int*   ntype   = (const int*)  d_in[1];
    const int*   src     = (const int*)  d_in[2];
    const int*   dst     = (const int*)  d_in[3];
    const int*   et      = (const int*)  d_in[4];
    const float* k_lin   = (const float*)d_in[5];
    const float* q_lin   = (const float*)d_in[6];
    const float* v_lin   = (const float*)d_in[7];
    const float* a_lin   = (const float*)d_in[8];
    const float* rel_att = (const float*)d_in[9];
    const float* rel_msg = (const float*)d_in[10];
    const float* rel_pri = (const float*)d_in[11];
    const float* skip    = (const float*)d_in[12];

    int N = in_sizes[1];
    int E = in_sizes[2];
    int M = N * NR;
    int ocap = N + NT * 64;

    float* ws = (float*)d_ws;
    size_t o = 0;
    unsigned short* kbf = (unsigned short*)(ws + o); o += (size_t)N * DIM / 2;
    float* q    = ws + o; o += (size_t)N * DIM;      // agg overlays q later
    float* v    = ws + o; o += (size_t)N * DIM;
    float* ex   = ws + o; o += (size_t)E;
    float* den  = ws + o; o += (size_t)N;
    int* off8   = (int*)(ws + o); o += (size_t)M + 8;
    int* cnt8   = (int*)(ws + o); o += (size_t)M;
    int* cnt28  = (int*)(ws + o); o += (size_t)M;
    int* se     = (int*)(ws + o); o += (size_t)E;
    int* bsum   = (int*)(ws + o); o += 1024;
    int* order  = (int*)(ws + o); o += (size_t)ocap;
    int* tm     = (int*)(ws + o); o += 16;
    unsigned short* rbuf = (unsigned short*)(ws + o);  // 8 x [N x DIM] bf16 = N*DIM*4 floats
    float* agg  = q;   // q dead after score phase

    float* out = (float*)d_out;

    // ---- type sort ----
    init_order<<<(ocap + 255) / 256, 256, 0, stream>>>(order, tm, ocap);
    type_count<<<(N + 255) / 256, 256, 0, stream>>>(ntype, tm, N);
    type_scan<<<1, 64, 0, stream>>>(tm);
    type_scatter<<<(N + 255) / 256, 256, 0, stream>>>(ntype, tm, order, N);

    // ---- typed fused projections (k -> bf16, q/v -> fp32) ----
    int gridT = (N + NT * 64 + 63) / 64;
    proj_typed<<<gridT, 256, 0, stream>>>(h, ntype, order, tm, k_lin, q_lin, v_lin,
                                          kbf, q, v, N);

    // ---- CSR build over (dst, etype) buckets ----
    init_cnt8<<<(M + 255) / 256, 256, 0, stream>>>(cnt8, cnt28, M);
    hist8<<<(E + 255) / 256, 256, 0, stream>>>(dst, et, cnt8, E);
    int nb = (M + 1023) / 1024;
    scan1<<<nb, 1024, 0, stream>>>(cnt8, off8, bsum, M);
    scan2<<<1, 1024, 0, stream>>>(bsum, nb);
    scan3<<<nb, 1024, 0, stream>>>(off8, bsum, M, E);
    scatter8<<<(E + 255) / 256, 256, 0, stream>>>(src, dst, et, off8, cnt28, se, E);

    int nb16 = (N + 15) / 16;
    int nb64 = (N + 63) / 64;

    // ---- score phase: qW (all 8 rel, bf16) then bucketed gather walk ----
    apply_rel8<<<nb64, 256, 0, stream>>>(q, rel_att, rbuf, N);
    score_b<<<nb16, 256, 0, stream>>>(rbuf, kbf, se, off8, rel_pri, ex, den, N);

    // ---- aggregate phase: vW (all 8 rel, bf16) then bucketed gather walk ----
    apply_rel8<<<nb64, 256, 0, stream>>>(v, rel_msg, rbuf, N);
    agg_b<<<nb16, 256, 0, stream>>>(rbuf, ex, se, off8, den, agg, N);

    // ---- typed output GEMM ----
    out_typed<<<gridT, 256, 0, stream>>>(agg, ntype, order, tm, a_lin, skip, out, N);
}

// Round 11
// 713.069 us; speedup vs baseline: 1.3763x; 1.2534x over previous
//
#include <hip/hip_runtime.h>
#include <math.h>

#define DIM 64
#define NT 4
#define NR 8
// tmeta layout: [0..3]=tcnt  [4..7]=tbase  [8..11]=tfill  [12]=padded_total

typedef __attribute__((ext_vector_type(8))) short bf16x8;   // 8 bf16 (4 VGPRs)
typedef __attribute__((ext_vector_type(4))) float f32x4;    // 4 fp32 acc

// ---- bf16 helpers (bit-level; values finite/small) ----
__device__ __forceinline__ unsigned short f2bf(float f) {
    unsigned u = __float_as_uint(f);
    return (unsigned short)((u + 0x7FFF + ((u >> 16) & 1)) >> 16);  // RNE
}
__device__ __forceinline__ float bf2f(unsigned short u) {
    return __uint_as_float((unsigned)u << 16);
}
__device__ __forceinline__ float4 bf4_to_f4(ushort4 u) {
    float4 f;
    f.x = bf2f(u.x); f.y = bf2f(u.y); f.z = bf2f(u.z); f.w = bf2f(u.w);
    return f;
}

__global__ void init_cnt8(int* __restrict__ cnt, int* __restrict__ cnt2, int M) {
    int i = blockIdx.x * blockDim.x + threadIdx.x;
    if (i < M) { cnt[i] = 0; cnt2[i] = 0; }
}

__global__ void init_order(int* __restrict__ order, int* __restrict__ tm, int cap) {
    int i = blockIdx.x * blockDim.x + threadIdx.x;
    if (i < cap) order[i] = -1;
    if (i < 16) tm[i] = 0;
}

// ---- per-wave ballot histogram of node types ----
__global__ void type_count(const int* __restrict__ ntype, int* __restrict__ tm, int N) {
    int i = blockIdx.x * blockDim.x + threadIdx.x;
    int t = (i < N) ? ntype[i] : -1;
    int lane = threadIdx.x & 63;
    #pragma unroll
    for (int tt = 0; tt < NT; tt++) {
        unsigned long long m = __ballot(t == tt);
        int c = __popcll(m);
        if (c && lane == (__ffsll((long long)m) - 1)) atomicAdd(&tm[tt], c);
    }
}

__global__ void type_scan(int* __restrict__ tm) {
    if (threadIdx.x == 0 && blockIdx.x == 0) {
        int b = 0;
        for (int t = 0; t < NT; t++) { tm[4 + t] = b; b += ((tm[t] + 63) >> 6) << 6; }
        tm[12] = b;
    }
}

__global__ void type_scatter(const int* __restrict__ ntype, int* __restrict__ tm,
                             int* __restrict__ order, int N) {
    int i = blockIdx.x * blockDim.x + threadIdx.x;
    int t = (i < N) ? ntype[i] : -1;
    int lane = threadIdx.x & 63;
    #pragma unroll
    for (int tt = 0; tt < NT; tt++) {
        unsigned long long m = __ballot(t == tt);
        int c = __popcll(m);
        if (!c) continue;
        int ldr = __ffsll((long long)m) - 1;
        int base = 0;
        if (lane == ldr) base = atomicAdd(&tm[8 + tt], c);
        base = __shfl(base, ldr, 64);
        if (t == tt) {
            int rank = __popcll(m & ((1ull << lane) - 1ull));
            order[tm[4 + tt] + base + rank] = i;
        }
    }
}

// ---- typed K/Q/V projection: 64-node tile; all outputs bf16 ----
__global__ void proj_typed(const float* __restrict__ h, const int* __restrict__ ntype,
                           const int* __restrict__ order, const int* __restrict__ tm,
                           const float* __restrict__ Wk, const float* __restrict__ Wq,
                           const float* __restrict__ Wv,
                           unsigned short* __restrict__ kbf, unsigned short* __restrict__ qbf,
                           unsigned short* __restrict__ vbf, int N) {
    __shared__ float xs[64][68];
    __shared__ float wsm[64][64];
    int t  = threadIdx.x;
    int n0 = blockIdx.x * 64;
    if (n0 >= tm[12]) return;
    int first = order[n0];
    if (first < 0) return;
    int ty = ntype[first];

    #pragma unroll
    for (int i = 0; i < 4; i++) {
        int idx = t + 256 * i;
        int row = idx >> 4, c4 = idx & 15;
        int gn = order[n0 + row];
        float4 xv = make_float4(0.f, 0.f, 0.f, 0.f);
        if (gn >= 0) xv = ((const float4*)(h + (size_t)gn * DIM))[c4];
        ((float4*)&xs[row][0])[c4] = xv;
    }

    const float* Ws[3] = { Wk + (size_t)ty * DIM * DIM,
                           Wq + (size_t)ty * DIM * DIM,
                           Wv + (size_t)ty * DIM * DIM };
    unsigned short* Os[3] = { kbf, qbf, vbf };

    int og  = t & 15;
    int ng4 = (t >> 4) * 4;
    int g[4];
    #pragma unroll
    for (int j = 0; j < 4; j++) g[j] = order[n0 + ng4 + j];

    for (int mm = 0; mm < 3; mm++) {
        const float4* wg = (const float4*)Ws[mm];
        float4* wl = (float4*)&wsm[0][0];
        __syncthreads();
        #pragma unroll
        for (int i = 0; i < 4; i++) wl[t + 256 * i] = wg[t + 256 * i];
        __syncthreads();
        float4 a[4];
        #pragma unroll
        for (int j = 0; j < 4; j++) a[j] = make_float4(0.f, 0.f, 0.f, 0.f);
        #pragma unroll 8
        for (int d = 0; d < DIM; d++) {
            float4 wv = ((const float4*)&wsm[d][0])[og];
            #pragma unroll
            for (int j = 0; j < 4; j++) {
                float xx = xs[ng4 + j][d];
                a[j].x = fmaf(xx, wv.x, a[j].x); a[j].y = fmaf(xx, wv.y, a[j].y);
                a[j].z = fmaf(xx, wv.z, a[j].z); a[j].w = fmaf(xx, wv.w, a[j].w);
            }
        }
        unsigned short* ob = Os[mm];
        #pragma unroll
        for (int j = 0; j < 4; j++)
            if (g[j] >= 0)
                ((ushort4*)(ob + (size_t)g[j] * DIM))[og] =
                    make_ushort4(f2bf(a[j].x), f2bf(a[j].y), f2bf(a[j].z), f2bf(a[j].w));
    }
}

// ---- transpose + cast relation matrices: Wt[r][n][k] = bf16(W[r][k][n]) ----
__global__ void prep_w(const float* __restrict__ A, const float* __restrict__ Mw,
                       unsigned short* __restrict__ At, unsigned short* __restrict__ Mt) {
    int i = blockIdx.x * blockDim.x + threadIdx.x;
    if (i >= NR * DIM * DIM) return;
    int r = i >> 12;
    int idx = i & 4095;
    int n = idx >> 6;
    int k = idx & 63;
    At[i] = f2bf(A[(r << 12) + k * DIM + n]);
    Mt[i] = f2bf(Mw[(r << 12) + k * DIM + n]);
}

// ---------------- CSR build over (dst*8 + etype) buckets ----------------
__global__ void hist8(const int* __restrict__ dst, const int* __restrict__ et,
                      int* __restrict__ cnt, int E) {
    int e = blockIdx.x * blockDim.x + threadIdx.x;
    if (e < E) atomicAdd(&cnt[dst[e] * NR + et[e]], 1);
}

__global__ void scan1(const int* __restrict__ cnt, int* __restrict__ off,
                      int* __restrict__ bsum, int M) {
    __shared__ int buf[1024];
    int tid = threadIdx.x;
    int i = blockIdx.x * 1024 + tid;
    int x = (i < M) ? cnt[i] : 0;
    buf[tid] = x;
    __syncthreads();
    for (int s = 1; s < 1024; s <<= 1) {
        int t = (tid >= s) ? buf[tid - s] : 0;
        __syncthreads();
        buf[tid] += t;
        __syncthreads();
    }
    if (i < M) off[i] = buf[tid] - x;
    if (tid == 1023) bsum[blockIdx.x] = buf[1023];
}

__global__ void scan2(int* __restrict__ bsum, int nb) {
    __shared__ int buf[1024];
    __shared__ int carry;
    int tid = threadIdx.x;
    if (tid == 0) carry = 0;
    __syncthreads();
    for (int base = 0; base < nb; base += 1024) {
        int i = base + tid;
        int x = (i < nb) ? bsum[i] : 0;
        buf[tid] = x;
        __syncthreads();
        for (int s = 1; s < 1024; s <<= 1) {
            int t = (tid >= s) ? buf[tid - s] : 0;
            __syncthreads();
            buf[tid] += t;
            __syncthreads();
        }
        if (i < nb) bsum[i] = carry + buf[tid] - x;
        __syncthreads();
        if (tid == 1023) carry += buf[1023];
        __syncthreads();
    }
}

__global__ void scan3(int* __restrict__ off, const int* __restrict__ bsum, int M, int E) {
    int i = blockIdx.x * 1024 + threadIdx.x;
    if (i < M) off[i] += bsum[blockIdx.x];
    if (i == 0) off[M] = E;
}

__global__ void scatter8(const int* __restrict__ src, const int* __restrict__ dst,
                         const int* __restrict__ et, const int* __restrict__ off,
                         int* __restrict__ cnt2, int* __restrict__ se, int E) {
    int e = blockIdx.x * blockDim.x + threadIdx.x;
    if (e >= E) return;
    int key = dst[e] * NR + et[e];
    int p = off[key] + atomicAdd(&cnt2[key], 1);
    se[p] = src[e];
}

// ---- MFMA apply_rel: out[r][n][o] = bf16( x[n][:] @ W_r ), all 8 r per block ----
// x bf16 [N][64]; Wt bf16 [r][n][k] (transposed W). 4 waves, 64-node tile.
// A-frag: A[m=lane&15][k=quad*8+j]; B-frag: B[k=quad*8+j][n=lane&15] via Wt rows.
// C/D: col=lane&15, row=quad*4+reg.
__global__ void apply_rel8_mfma(const unsigned short* __restrict__ xbf,
                                const unsigned short* __restrict__ Wt,
                                unsigned short* __restrict__ out, int N) {
    __shared__ unsigned short xs[64][72];   // 144B rows: 16B-aligned, 2-way bank alias only
    __shared__ unsigned short wsm[64][72];
    int t = threadIdx.x;
    int n0 = blockIdx.x * 64;
    int wave = t >> 6;
    int lane = t & 63;
    int m    = lane & 15;
    int quad = lane >> 4;

    // stage x tile: 64 rows x 8 uint4-chunks; 2 chunks per thread
    #pragma unroll
    for (int i = 0; i < 2; i++) {
        int idx = t + 256 * i;
        int row = idx >> 3, c8 = idx & 7;
        int gn = n0 + row;
        uint4 val = make_uint4(0u, 0u, 0u, 0u);
        if (gn < N) val = ((const uint4*)(xbf + (size_t)gn * DIM))[c8];
        *((uint4*)&xs[row][c8 * 8]) = val;
    }

    for (int r = 0; r < NR; r++) {
        __syncthreads();   // prev iter's MFMA reads of wsm done; (iter 0: xs staged)
        const unsigned short* wg = Wt + (size_t)r * DIM * DIM;
        #pragma unroll
        for (int i = 0; i < 2; i++) {
            int idx = t + 256 * i;
            int row = idx >> 3, c8 = idx & 7;
            *((uint4*)&wsm[row][c8 * 8]) = ((const uint4*)(wg + row * DIM))[c8];
        }
        __syncthreads();

        f32x4 acc0 = {0.f, 0.f, 0.f, 0.f}, acc1 = acc0, acc2 = acc0, acc3 = acc0;
        #pragma unroll
        for (int k0 = 0; k0 < DIM; k0 += 32) {
            bf16x8 a = *((const bf16x8*)&xs[16 * wave + m][k0 + quad * 8]);
            bf16x8 b0 = *((const bf16x8*)&wsm[ 0 + m][k0 + quad * 8]);
            bf16x8 b1 = *((const bf16x8*)&wsm[16 + m][k0 + quad * 8]);
            bf16x8 b2 = *((const bf16x8*)&wsm[32 + m][k0 + quad * 8]);
            bf16x8 b3 = *((const bf16x8*)&wsm[48 + m][k0 + quad * 8]);
            acc0 = __builtin_amdgcn_mfma_f32_16x16x32_bf16(a, b0, acc0, 0, 0, 0);
            acc1 = __builtin_amdgcn_mfma_f32_16x16x32_bf16(a, b1, acc1, 0, 0, 0);
            acc2 = __builtin_amdgcn_mfma_f32_16x16x32_bf16(a, b2, acc2, 0, 0, 0);
            acc3 = __builtin_amdgcn_mfma_f32_16x16x32_bf16(a, b3, acc3, 0, 0, 0);
        }

        unsigned short* ob = out + (size_t)r * N * DIM;
        #pragma unroll
        for (int reg = 0; reg < 4; reg++) {
            int gr = n0 + 16 * wave + quad * 4 + reg;
            if (gr < N) {
                unsigned short* row = ob + (size_t)gr * DIM + m;
                row[ 0] = f2bf(acc0[reg]);
                row[16] = f2bf(acc1[reg]);
                row[32] = f2bf(acc2[reg]);
                row[48] = f2bf(acc3[reg]);
            }
        }
    }
}

// ---- score over bucketed CSR: 16-lane group per node; qW row hoisted per bucket ----
__global__ void score_b(const unsigned short* __restrict__ qW,
                        const unsigned short* __restrict__ kbf,
                        const int* __restrict__ se, const int* __restrict__ off8,
                        const float* __restrict__ rel_pri,
                        float* __restrict__ ex, float* __restrict__ den, int N) {
    int t = threadIdx.x;
    int node = t >> 4;
    int ll   = t & 15;
    int n = blockIdx.x * 16 + node;
    if (n >= N) return;
    int ov = (ll < 9) ? off8[n * NR + ll] : 0;
    float dl = 0.f;
    #pragma unroll
    for (int r = 0; r < NR; r++) {
        int i0 = __shfl(ov, r, 16);
        int i1 = __shfl(ov, r + 1, 16);
        if (i0 == i1) continue;
        float4 tv = bf4_to_f4(((const ushort4*)(qW + ((size_t)r * N + n) * DIM))[ll]);
        float pri = rel_pri[r] * 0.125f;
        for (int i = i0; i < i1; i++) {
            int s = se[i];
            float4 kv = bf4_to_f4(((const ushort4*)(kbf + (size_t)s * DIM))[ll]);
            float p = tv.x * kv.x + tv.y * kv.y + tv.z * kv.z + tv.w * kv.w;
            p += __shfl_xor(p, 8, 16);
            p += __shfl_xor(p, 4, 16);
            p += __shfl_xor(p, 2, 16);
            p += __shfl_xor(p, 1, 16);
            if (ll == 0) {
                float e_ = expf(p * pri);   // logits tiny by input scaling: no max-shift
                ex[i] = e_;
                dl += e_;
            }
        }
    }
    if (ll == 0) den[n] = dl;
}

// ---- aggregate over bucketed CSR: single float4 accumulator per lane ----
__global__ void agg_b(const unsigned short* __restrict__ vW, const float* __restrict__ ex,
                      const int* __restrict__ se, const int* __restrict__ off8,
                      const float* __restrict__ den, float* __restrict__ agg, int N) {
    int t = threadIdx.x;
    int node = t >> 4;
    int ll   = t & 15;
    int n = blockIdx.x * 16 + node;
    if (n >= N) return;
    int ov = (ll < 9) ? off8[n * NR + ll] : 0;
    float dn = den[n];
    float inv = (dn == 0.f) ? 0.f : 1.f / dn;
    float4 acc = make_float4(0.f, 0.f, 0.f, 0.f);
    #pragma unroll
    for (int r = 0; r < NR; r++) {
        int i0 = __shfl(ov, r, 16);
        int i1 = __shfl(ov, r + 1, 16);
        const unsigned short* vr = vW + (size_t)r * N * DIM;
        for (int i = i0; i < i1; i++) {
            int s = se[i];
            float alpha = ex[i] * inv;
            float4 mv = bf4_to_f4(((const ushort4*)(vr + (size_t)s * DIM))[ll]);
            acc.x = fmaf(alpha, mv.x, acc.x);
            acc.y = fmaf(alpha, mv.y, acc.y);
            acc.z = fmaf(alpha, mv.z, acc.z);
            acc.w = fmaf(alpha, mv.w, acc.w);
        }
    }
    ((float4*)(agg + (size_t)n * DIM))[ll] = acc;
}

// ------- typed output GEMM: 64-node tile, sigmoid(skip)*W staged in LDS -------
__global__ void out_typed(const float* __restrict__ agg, const int* __restrict__ ntype,
                          const int* __restrict__ order, const int* __restrict__ tm,
                          const float* __restrict__ Wa, const float* __restrict__ skip,
                          float* __restrict__ out, int N) {
    __shared__ float xs[64][68];
    __shared__ float wsm[64][64];
    int t  = threadIdx.x;
    int n0 = blockIdx.x * 64;
    if (n0 >= tm[12]) return;
    int first = order[n0];
    if (first < 0) return;
    int ty = ntype[first];
    float sg = 1.f / (1.f + expf(-skip[ty]));

    const float4* wg = (const float4*)(Wa + (size_t)ty * DIM * DIM);
    float4* wl = (float4*)&wsm[0][0];
    #pragma unroll
    for (int i = 0; i < 4; i++) {
        float4 w = wg[t + 256 * i];
        w.x *= sg; w.y *= sg; w.z *= sg; w.w *= sg;
        wl[t + 256 * i] = w;
    }
    #pragma unroll
    for (int i = 0; i < 4; i++) {
        int idx = t + 256 * i;
        int row = idx >> 4, c4 = idx & 15;
        int gn = order[n0 + row];
        float4 xv = make_float4(0.f, 0.f, 0.f, 0.f);
        if (gn >= 0) xv = ((const float4*)(agg + (size_t)gn * DIM))[c4];
        ((float4*)&xs[row][0])[c4] = xv;
    }
    __syncthreads();

    int og  = t & 15;
    int ng4 = (t >> 4) * 4;
    float4 a0 = make_float4(0.f,0.f,0.f,0.f), a1 = a0, a2 = a0, a3 = a0;
    #pragma unroll 8
    for (int d = 0; d < DIM; d++) {
        float4 wv = ((const float4*)&wsm[d][0])[og];
        float x0 = xs[ng4 + 0][d];
        float x1 = xs[ng4 + 1][d];
        float x2 = xs[ng4 + 2][d];
        float x3 = xs[ng4 + 3][d];
        a0.x = fmaf(x0, wv.x, a0.x); a0.y = fmaf(x0, wv.y, a0.y);
        a0.z = fmaf(x0, wv.z, a0.z); a0.w = fmaf(x0, wv.w, a0.w);
        a1.x = fmaf(x1, wv.x, a1.x); a1.y = fmaf(x1, wv.y, a1.y);
        a1.z = fmaf(x1, wv.z, a1.z); a1.w = fmaf(x1, wv.w, a1.w);
        a2.x = fmaf(x2, wv.x, a2.x); a2.y = fmaf(x2, wv.y, a2.y);
        a2.z = fmaf(x2, wv.z, a2.z); a2.w = fmaf(x2, wv.w, a2.w);
        a3.x = fmaf(x3, wv.x, a3.x); a3.y = fmaf(x3, wv.y, a3.y);
        a3.z = fmaf(x3, wv.z, a3.z); a3.w = fmaf(x3, wv.w, a3.w);
    }
    int g0 = order[n0 + ng4 + 0];
    int g1 = order[n0 + ng4 + 1];
    int g2 = order[n0 + ng4 + 2];
    int g3 = order[n0 + ng4 + 3];
    if (g0 >= 0) ((float4*)(out + (size_t)g0 * DIM))[og] = a0;
    if (g1 >= 0) ((float4*)(out + (size_t)g1 * DIM))[og] = a1;
    if (g2 >= 0) ((float4*)(out + (size_t)g2 * DIM))[og] = a2;
    if (g3 >= 0) ((float4*)(out + (size_t)g3 * DIM))[og] = a3;
}

extern "C" void kernel_launch(void* const* d_in, const int* in_sizes, int n_in,
                              void* d_out, int out_size, void* d_ws, size_t ws_size,
                              hipStream_t stream) {
    const float* h       = (const float*)d_in[0];
    const int*   ntype   = (const int*)  d_in[1];
    const int*   src     = (const int*)  d_in[2];
    const int*   dst     = (const int*)  d_in[3];
    const int*   et      = (const int*)  d_in[4];
    const float* k_lin   = (const float*)d_in[5];
    const float* q_lin   = (const float*)d_in[6];
    const float* v_lin   = (const float*)d_in[7];
    const float* a_lin   = (const float*)d_in[8];
    const float* rel_att = (const float*)d_in[9];
    const float* rel_msg = (const float*)d_in[10];
    const float* rel_pri = (const float*)d_in[11];
    const float* skip    = (const float*)d_in[12];

    int N = in_sizes[1];
    int E = in_sizes[2];
    int M = N * NR;
    int ocap = N + NT * 64;

    float* ws = (float*)d_ws;
    size_t o = 0;
    unsigned short* kbf = (unsigned short*)(ws + o); o += (size_t)N * DIM / 2;
    unsigned short* qbf = (unsigned short*)(ws + o); o += (size_t)N * DIM / 2;
    unsigned short* vbf = (unsigned short*)(ws + o); o += (size_t)N * DIM / 2;
    float* ex   = ws + o; o += (size_t)E;
    float* den  = ws + o; o += (size_t)N;
    float* agg  = ws + o; o += (size_t)N * DIM;
    int* off8   = (int*)(ws + o); o += (size_t)M + 8;
    int* cnt8   = (int*)(ws + o); o += (size_t)M;
    int* cnt28  = (int*)(ws + o); o += (size_t)M;
    int* se     = (int*)(ws + o); o += (size_t)E;
    int* bsum   = (int*)(ws + o); o += 1024;
    int* order  = (int*)(ws + o); o += (size_t)ocap;
    int* tm     = (int*)(ws + o); o += 16;
    unsigned short* At = (unsigned short*)(ws + o); o += (size_t)NR * DIM * DIM / 2;
    unsigned short* Mt = (unsigned short*)(ws + o); o += (size_t)NR * DIM * DIM / 2;
    unsigned short* rbuf = (unsigned short*)(ws + o);  // 8 x [N x DIM] bf16

    float* out = (float*)d_out;

    // ---- type sort ----
    init_order<<<(ocap + 255) / 256, 256, 0, stream>>>(order, tm, ocap);
    type_count<<<(N + 255) / 256, 256, 0, stream>>>(ntype, tm, N);
    type_scan<<<1, 64, 0, stream>>>(tm);
    type_scatter<<<(N + 255) / 256, 256, 0, stream>>>(ntype, tm, order, N);

    // ---- typed fused projections (k,q,v -> bf16) ----
    int gridT = (N + NT * 64 + 63) / 64;
    proj_typed<<<gridT, 256, 0, stream>>>(h, ntype, order, tm, k_lin, q_lin, v_lin,
                                          kbf, qbf, vbf, N);

    // ---- relation weight transpose+cast (for MFMA B-operand) ----
    prep_w<<<(NR * DIM * DIM + 255) / 256, 256, 0, stream>>>(rel_att, rel_msg, At, Mt);

    // ---- CSR build over (dst, etype) buckets ----
    init_cnt8<<<(M + 255) / 256, 256, 0, stream>>>(cnt8, cnt28, M);
    hist8<<<(E + 255) / 256, 256, 0, stream>>>(dst, et, cnt8, E);
    int nb = (M + 1023) / 1024;
    scan1<<<nb, 1024, 0, stream>>>(cnt8, off8, bsum, M);
    scan2<<<1, 1024, 0, stream>>>(bsum, nb);
    scan3<<<nb, 1024, 0, stream>>>(off8, bsum, M, E);
    scatter8<<<(E + 255) / 256, 256, 0, stream>>>(src, dst, et, off8, cnt28, se, E);

    int nb16 = (N + 15) / 16;
    int nb64 = (N + 63) / 64;

    // ---- score phase: qW via MFMA, then bucketed gather walk ----
    apply_rel8_mfma<<<nb64, 256, 0, stream>>>(qbf, At, rbuf, N);
    score_b<<<nb16, 256, 0, stream>>>(rbuf, kbf, se, off8, rel_pri, ex, den, N);

    // ---- aggregate phase: vW via MFMA, then bucketed gather walk ----
    apply_rel8_mfma<<<nb64, 256, 0, stream>>>(vbf, Mt, rbuf, N);
    agg_b<<<nb16, 256, 0, stream>>>(rbuf, ex, se, off8, den, agg, N);

    // ---- typed output GEMM ----
    out_typed<<<gridT, 256, 0, stream>>>(agg, ntype, order, tm, a_lin, skip, out, N);
}